// Round 6
// baseline (334.214 us; speedup 1.0000x reference)
//
#include <hip/hip_runtime.h>

// B=4, N=4096, E=2048, C=64.
// H is BINARY -> bit-pack it. Pipeline:
//  k_transform: xtT[b][o][n] bf16 (2 MB)
//  k_prep:      read H fp32 once (134 MB, the traffic floor), emit
//               Hbits[b][n][E/64 u64] (4 MB), HbitsT[b][e][N/64 u64] (4 MB)
//               via __ballot + LDS bit-transpose, deg_e/deg_n via popcount.
//  k_edge:      heT partials: A=xtT (direct 16B loads), B=HbitsT bytes
//               expanded to bf16 in regs. NO LDS, NO barriers. K-split x8.
//  k_henorm:    combine partials / deg_e -> heT bf16 (1 MB)
//  k_node:      out partials: A=Hbits bytes expanded, B=heT direct loads.
//               NO LDS, NO barriers. K-split x4.
//  k_final:     combine / deg_n + bias.
#define B_ 4
#define N_ 4096
#define E_ 2048

typedef __attribute__((ext_vector_type(8))) short short8;   // 8 bf16
typedef __attribute__((ext_vector_type(4))) float float4v;  // MFMA C/D

// round-to-nearest-even f32 -> bf16 bits
static __device__ __forceinline__ unsigned short f2bf(float f) {
  union { float f; unsigned int u; } v; v.f = f;
  unsigned int r = (v.u + 0x7FFFu + ((v.u >> 16) & 1u)) >> 16;
  return (unsigned short)r;
}

// expand 8 H-bits -> 8 bf16 values {0.0, 1.0}
static __device__ __forceinline__ short8 expand8(unsigned int by) {
  short8 r;
#pragma unroll
  for (int j = 0; j < 8; ++j)
    r[j] = (short)(((by >> j) & 1u) ? 0x3F80 : 0);
  return r;
}

// ---------------------------------------------------------------------------
// K1: xtT[b][o][n] = bf16( sum_k x[b][n][k] * theta[k][o] )   (transposed)
// ---------------------------------------------------------------------------
__global__ __launch_bounds__(256) void k_transform(
    const float* __restrict__ x, const float* __restrict__ theta,
    unsigned short* __restrict__ xtT) {
  __shared__ unsigned short ldsT[64][72];
  int t = threadIdx.x;
  int nt = blockIdx.x & 63, b = blockIdx.x >> 6;
  int n0 = nt * 64;
  int o = t & 63, nq = t >> 6;
#pragma unroll 4
  for (int i = 0; i < 16; ++i) {
    int n = n0 + nq * 16 + i;
    const float* xr = x + ((size_t)(b * N_ + n) << 6);
    float acc = 0.f;
#pragma unroll
    for (int k = 0; k < 64; ++k) acc += xr[k] * theta[k * 64 + o];
    ldsT[o][nq * 16 + i] = f2bf(acc);
  }
  __syncthreads();
  int orow = t >> 2, c = (t & 3) * 16;
  unsigned short* dst = xtT + ((size_t)(b * 64 + orow) << 12) + n0 + c;
  *(uint4*)dst = *(const uint4*)&ldsT[orow][c];
  *(uint4*)(dst + 8) = *(const uint4*)&ldsT[orow][c + 8];
}

// ---------------------------------------------------------------------------
// K2: bit-pack H both orientations + exact degrees.
// grid 1024 = et(4: 512-e chunk) x nt(64: 64-n tile) x b(4).
// Phase 1: row-mode coalesced reads (256 B/instr), __ballot -> 64-bit masks
//          (bit i = lane i = e-offset i), popcount -> deg_n.
// Phase 2: ballot-based 64x64 bit-transpose from LDS -> HbitsT + deg_e.
// Phase 3: coalesced copy-out of n-major words -> Hbits.
// ---------------------------------------------------------------------------
__global__ __launch_bounds__(256) void k_prep(
    const float* __restrict__ H, unsigned long long* __restrict__ Hbits,
    unsigned long long* __restrict__ HbitsT, float* __restrict__ deg_e,
    float* __restrict__ deg_n) {
  __shared__ unsigned long long ldsBits[64][9];  // [n_local][e_word], padded
  int t = threadIdx.x;
  int et = blockIdx.x & 3, nt = (blockIdx.x >> 2) & 63, b = blockIdx.x >> 8;
  int e0 = et * 512, n0 = nt * 64;
  int w = t >> 6, lane = t & 63;

  const float* src = H + ((size_t)(b * N_ + n0 + w * 16)) * E_ + e0 + lane;
  for (int r = 0; r < 16; ++r) {
    unsigned int cnt = 0;
#pragma unroll
    for (int wd = 0; wd < 8; ++wd) {
      float v = src[wd * 64];
      unsigned long long m = __ballot(v != 0.0f);
      if (lane == 0) ldsBits[w * 16 + r][wd] = m;
      cnt += (unsigned int)__popcll(m);
    }
    if (lane == 0) atomicAdd(&deg_n[b * N_ + n0 + w * 16 + r], (float)cnt);
    src += E_;
  }
  __syncthreads();
  // phase 2: wave w transposes e-words 2w, 2w+1 (64 e each)
#pragma unroll
  for (int p = 0; p < 2; ++p) {
    int wd = w * 2 + p;
    unsigned long long col = ldsBits[lane][wd];  // lane = n_local
    unsigned long long mine = 0;
#pragma unroll
    for (int bit = 0; bit < 64; ++bit) {
      unsigned long long m = __ballot((col >> bit) & 1ull);  // bit i = n0+i
      if (lane == bit) mine = m;
    }
    int e = e0 + wd * 64 + lane;
    HbitsT[(((size_t)(b * E_ + e)) << 6) + nt] = mine;
    atomicAdd(&deg_e[b * E_ + e], (float)__popcll(mine));
  }
  // phase 3: copy n-major words out (LDS already complete pre-sync)
  int i = t * 2;
  int row = i >> 3, wd2 = i & 7;
  unsigned long long* dst =
      Hbits + (((size_t)(b * N_ + n0 + row)) << 5) + et * 8 + wd2;
  dst[0] = ldsBits[row][wd2];
  dst[1] = ldsBits[row][wd2 + 1];
}

// ---------------------------------------------------------------------------
// K3 (phase A GEMM): p_he[ks][b][o][e] = sum_{n chunk} xtT[o][n]*H[n][e]
// grid 1024 = ks(8) x et(32) x b(4); 64o x 64e per block, BK=64, 8 iters.
// A: direct 16B global loads from xtT (L2). B: HbitsT bytes -> bf16 in regs.
// No LDS, no barriers; 1-deep register prefetch.
// ---------------------------------------------------------------------------
__global__ __launch_bounds__(256) void k_edge(
    const unsigned short* __restrict__ xtT,
    const unsigned long long* __restrict__ HbitsT,
    float* __restrict__ p_he) {
  int t = threadIdx.x;
  int ks = blockIdx.x & 7, et = (blockIdx.x >> 3) & 31, b = blockIdx.x >> 8;
  int e0 = et * 64;
  int w = t >> 6, lane = t & 63, quad = lane >> 4, m15 = lane & 15;
  int o = w * 16 + m15;

  const unsigned short* gA =
      xtT + ((size_t)(b * 64 + o) << 12) + ks * 512 + quad * 8;
  const unsigned long long* gBt =
      HbitsT + (((size_t)(b * E_ + e0 + m15)) << 6) + ks * 8;

  float4v acc[4];
#pragma unroll
  for (int ct = 0; ct < 4; ++ct) acc[ct] = (float4v){0.f, 0.f, 0.f, 0.f};

  short8 a0 = *(const short8*)(gA);
  short8 a1 = *(const short8*)(gA + 32);
  unsigned long long u0 = gBt[0], u1 = gBt[1024], u2 = gBt[2048],
                     u3 = gBt[3072];

  for (int kt = 0; kt < 8; ++kt) {
    short8 na0, na1;
    unsigned long long v0 = 0, v1 = 0, v2 = 0, v3 = 0;
    if (kt < 7) {
      const unsigned short* ga = gA + (kt + 1) * 64;
      na0 = *(const short8*)(ga);
      na1 = *(const short8*)(ga + 32);
      v0 = gBt[kt + 1];        v1 = gBt[kt + 1 + 1024];
      v2 = gBt[kt + 1 + 2048]; v3 = gBt[kt + 1 + 3072];
    }
#pragma unroll
    for (int s = 0; s < 2; ++s) {
      short8 a = s ? a1 : a0;
      int sh = (s * 4 + quad) << 3;
      acc[0] = __builtin_amdgcn_mfma_f32_16x16x32_bf16(
          a, expand8((unsigned int)(u0 >> sh) & 0xFFu), acc[0], 0, 0, 0);
      acc[1] = __builtin_amdgcn_mfma_f32_16x16x32_bf16(
          a, expand8((unsigned int)(u1 >> sh) & 0xFFu), acc[1], 0, 0, 0);
      acc[2] = __builtin_amdgcn_mfma_f32_16x16x32_bf16(
          a, expand8((unsigned int)(u2 >> sh) & 0xFFu), acc[2], 0, 0, 0);
      acc[3] = __builtin_amdgcn_mfma_f32_16x16x32_bf16(
          a, expand8((unsigned int)(u3 >> sh) & 0xFFu), acc[3], 0, 0, 0);
    }
    if (kt < 7) { a0 = na0; a1 = na1; u0 = v0; u1 = v1; u2 = v2; u3 = v3; }
  }
  float* dst = p_he + (size_t)ks * (B_ * 64 * E_);
#pragma unroll
  for (int ct = 0; ct < 4; ++ct)
#pragma unroll
    for (int r = 0; r < 4; ++r) {
      int oo = w * 16 + quad * 4 + r;
      dst[((size_t)(b * 64 + oo)) * E_ + e0 + ct * 16 + m15] = acc[ct][r];
    }
}

// ---------------------------------------------------------------------------
// K4: heT[b][o][e] = bf16( (sum_ks p_he[ks]) / deg_e[b][e] )
// ---------------------------------------------------------------------------
__global__ __launch_bounds__(256) void k_henorm(
    const float* __restrict__ p_he, const float* __restrict__ deg_e,
    unsigned short* __restrict__ heT) {
  int idx = (blockIdx.x * 256 + threadIdx.x) * 4;  // over B*64*E = 524288
  int e = idx & (E_ - 1);
  int b = idx >> 17;
  float4 s = *(const float4*)(p_he + idx);
#pragma unroll
  for (int k = 1; k < 8; ++k) {
    float4 sk = *(const float4*)(p_he + (size_t)k * (B_ * 64 * E_) + idx);
    s.x += sk.x; s.y += sk.y; s.z += sk.z; s.w += sk.w;
  }
  float4 d = *(const float4*)(deg_e + b * E_ + e);
  unsigned int lo = (unsigned int)f2bf(s.x / d.x) |
                    ((unsigned int)f2bf(s.y / d.y) << 16);
  unsigned int hi = (unsigned int)f2bf(s.z / d.z) |
                    ((unsigned int)f2bf(s.w / d.w) << 16);
  uint2 u; u.x = lo; u.y = hi;
  *(uint2*)(heT + idx) = u;
}

// ---------------------------------------------------------------------------
// K5 (phase B GEMM): q[ks][b][n][o] = sum_{e chunk} H[n][e]*heT[o][e]
// grid 1024 = ks(4) x mt(64) x b(4); 64n x 64o per block, BK=64, 8 iters.
// A: Hbits bytes -> bf16 in regs. B: direct 16B global loads from heT (L2).
// No LDS, no barriers; 1-deep register prefetch.
// ---------------------------------------------------------------------------
__global__ __launch_bounds__(256) void k_node(
    const unsigned long long* __restrict__ Hbits,
    const unsigned short* __restrict__ heT, float* __restrict__ q) {
  int t = threadIdx.x;
  int ks = blockIdx.x & 3, mt = (blockIdx.x >> 2) & 63, b = blockIdx.x >> 8;
  int n0 = mt * 64;
  int w = t >> 6, lane = t & 63, quad = lane >> 4, m15 = lane & 15;
  int n = n0 + w * 16 + m15;

  const unsigned long long* gAb =
      Hbits + (((size_t)(b * N_ + n)) << 5) + ks * 8;
  const unsigned short* gB =
      heT + ((size_t)(b * 64 + m15) << 11) + ks * 512 + quad * 8;

  float4v acc[4];
#pragma unroll
  for (int ct = 0; ct < 4; ++ct) acc[ct] = (float4v){0.f, 0.f, 0.f, 0.f};

  unsigned long long ua = gAb[0];
  short8 bb[8];
#pragma unroll
  for (int ct = 0; ct < 4; ++ct)
#pragma unroll
    for (int s = 0; s < 2; ++s)
      bb[ct * 2 + s] = *(const short8*)(gB + ct * 32768 + s * 32);

  for (int kt = 0; kt < 8; ++kt) {
    unsigned long long va = 0;
    short8 nb[8];
    if (kt < 7) {
      va = gAb[kt + 1];
      const unsigned short* g = gB + (kt + 1) * 64;
#pragma unroll
      for (int ct = 0; ct < 4; ++ct)
#pragma unroll
        for (int s = 0; s < 2; ++s)
          nb[ct * 2 + s] = *(const short8*)(g + ct * 32768 + s * 32);
    }
#pragma unroll
    for (int s = 0; s < 2; ++s) {
      int sh = (s * 4 + quad) << 3;
      short8 a = expand8((unsigned int)(ua >> sh) & 0xFFu);
#pragma unroll
      for (int ct = 0; ct < 4; ++ct)
        acc[ct] = __builtin_amdgcn_mfma_f32_16x16x32_bf16(a, bb[ct * 2 + s],
                                                          acc[ct], 0, 0, 0);
    }
    if (kt < 7) {
      ua = va;
#pragma unroll
      for (int i2 = 0; i2 < 8; ++i2) bb[i2] = nb[i2];
    }
  }
  float* dst = q + (size_t)ks * ((size_t)B_ * N_ * 64);
#pragma unroll
  for (int r = 0; r < 4; ++r) {
    int row = w * 16 + quad * 4 + r;
    int nn = n0 + row;
#pragma unroll
    for (int ct = 0; ct < 4; ++ct)
      dst[(((size_t)(b * N_ + nn)) << 6) + ct * 16 + m15] = acc[ct][r];
  }
}

// ---------------------------------------------------------------------------
// K6: out[b][n][o] = (sum_ks q[ks]) / deg_n[b][n] + bias[o]
// ---------------------------------------------------------------------------
__global__ __launch_bounds__(256) void k_final(
    const float* __restrict__ q, const float* __restrict__ deg_n,
    const float* __restrict__ bias, float* __restrict__ out) {
  int idx = (blockIdx.x * 256 + threadIdx.x) * 4;  // over B*N*64 = 1048576
  int o = idx & 63;
  int bn = idx >> 6;
  float4 s = *(const float4*)(q + idx);
#pragma unroll
  for (int k = 1; k < 4; ++k) {
    float4 sk = *(const float4*)(q + (size_t)k * ((size_t)B_ * N_ * 64) + idx);
    s.x += sk.x; s.y += sk.y; s.z += sk.z; s.w += sk.w;
  }
  float4 bv = *(const float4*)(bias + o);
  float inv = 1.0f / deg_n[bn];
  float4 r;
  r.x = s.x * inv + bv.x; r.y = s.y * inv + bv.y;
  r.z = s.z * inv + bv.z; r.w = s.w * inv + bv.w;
  *(float4*)(out + idx) = r;
}

extern "C" void kernel_launch(void* const* d_in, const int* in_sizes, int n_in,
                              void* d_out, int out_size, void* d_ws, size_t ws_size,
                              hipStream_t stream) {
  const float* x     = (const float*)d_in[0];
  const float* H     = (const float*)d_in[1];
  const float* theta = (const float*)d_in[2];
  const float* bias  = (const float*)d_in[3];

  // ws (bytes): xtT 2MB | Hbits 4MB | HbitsT 4MB | p_he 16MB | heT 1MB |
  //             q 16MB | deg_e 32KB | deg_n 64KB   (~43 MB)
  char* ws = (char*)d_ws;
  unsigned short* xtT         = (unsigned short*)ws;
  unsigned long long* Hbits   = (unsigned long long*)(ws + 2097152);
  unsigned long long* HbitsT  = (unsigned long long*)(ws + 6291456);
  float* p_he                 = (float*)(ws + 10485760);
  unsigned short* heT         = (unsigned short*)(ws + 27262976);
  float* q                    = (float*)(ws + 28311552);
  float* deg_e                = (float*)(ws + 45088768);
  float* deg_n                = (float*)(ws + 45121536);

  hipMemsetAsync(deg_e, 0, 98304, stream);  // deg_e + deg_n (adjacent)
  k_transform<<<256, 256, 0, stream>>>(x, theta, xtT);
  k_prep<<<1024, 256, 0, stream>>>(H, Hbits, HbitsT, deg_e, deg_n);
  k_edge<<<1024, 256, 0, stream>>>(xtT, HbitsT, p_he);
  k_henorm<<<512, 256, 0, stream>>>(p_he, deg_e, heT);
  k_node<<<1024, 256, 0, stream>>>(Hbits, heT, q);
  k_final<<<1024, 256, 0, stream>>>(q, deg_n, bias, (float*)d_out);
}

// Round 7
// 268.582 us; speedup vs baseline: 1.2444x; 1.2444x over previous
//
#include <hip/hip_runtime.h>

// B=4, N=4096, E=2048, C=64.  H is binary -> bit-packed.
//  k_transform: xtT[b][o][n] bf16 (2 MB)
//  k_prep:      read H fp32 once (batched loads -> ballots), emit Hbits (4 MB),
//               HbitsT (4 MB), exact deg_e/deg_n via popcount.
//  k_edge:      heT partials: A=xtT staged via global_load_lds (coalesced),
//               B=HbitsT u64 direct + reg expand. K-split x8.
//  k_henorm:    combine/deg_e -> heT bf16 (1 MB)
//  k_node:      out partials: A=Hbits u64 direct + expand, B=heT staged via
//               global_load_lds. K-split x4.
//  k_final:     combine/deg_n + bias.
#define B_ 4
#define N_ 4096
#define E_ 2048

typedef __attribute__((ext_vector_type(8))) short short8;   // 8 bf16
typedef __attribute__((ext_vector_type(4))) float float4v;  // MFMA C/D

// round-to-nearest-even f32 -> bf16 bits
static __device__ __forceinline__ unsigned short f2bf(float f) {
  union { float f; unsigned int u; } v; v.f = f;
  unsigned int r = (v.u + 0x7FFFu + ((v.u >> 16) & 1u)) >> 16;
  return (unsigned short)r;
}

// expand 8 H-bits -> 8 bf16 values {0.0, 1.0}
static __device__ __forceinline__ short8 expand8(unsigned int by) {
  short8 r;
#pragma unroll
  for (int j = 0; j < 8; ++j)
    r[j] = (short)(((by >> j) & 1u) ? 0x3F80 : 0);
  return r;
}

static __device__ __forceinline__ void stage16(const void* g, void* l) {
  __builtin_amdgcn_global_load_lds(
      (const __attribute__((address_space(1))) unsigned int*)g,
      (__attribute__((address_space(3))) unsigned int*)l, 16, 0, 0);
}

// ---------------------------------------------------------------------------
// K1: xtT[b][o][n] = bf16( sum_k x[b][n][k] * theta[k][o] )   (transposed)
// ---------------------------------------------------------------------------
__global__ __launch_bounds__(256) void k_transform(
    const float* __restrict__ x, const float* __restrict__ theta,
    unsigned short* __restrict__ xtT) {
  __shared__ unsigned short ldsT[64][72];
  int t = threadIdx.x;
  int nt = blockIdx.x & 63, b = blockIdx.x >> 6;
  int n0 = nt * 64;
  int o = t & 63, nq = t >> 6;
#pragma unroll 4
  for (int i = 0; i < 16; ++i) {
    int n = n0 + nq * 16 + i;
    const float* xr = x + ((size_t)(b * N_ + n) << 6);
    float acc = 0.f;
#pragma unroll
    for (int k = 0; k < 64; ++k) acc += xr[k] * theta[k * 64 + o];
    ldsT[o][nq * 16 + i] = f2bf(acc);
  }
  __syncthreads();
  int orow = t >> 2, c = (t & 3) * 16;
  unsigned short* dst = xtT + ((size_t)(b * 64 + orow) << 12) + n0 + c;
  *(uint4*)dst = *(const uint4*)&ldsT[orow][c];
  *(uint4*)(dst + 8) = *(const uint4*)&ldsT[orow][c + 8];
}

// ---------------------------------------------------------------------------
// K2: bit-pack H + exact degrees. grid 1024 = et(4) x nt(64) x b(4).
// Phase 1: 32 loads hoisted into regs (one vmcnt drain), THEN 32 ballots —
//          kills the load->ballot serialization that made round-6 99 us.
// Phase 2: ballot 64x64 bit-transpose -> HbitsT + deg_e.
// Phase 3: coalesced copy-out -> Hbits.
// ---------------------------------------------------------------------------
__global__ __launch_bounds__(256) void k_prep(
    const float* __restrict__ H, unsigned long long* __restrict__ Hbits,
    unsigned long long* __restrict__ HbitsT, float* __restrict__ deg_e,
    float* __restrict__ deg_n) {
  __shared__ unsigned long long ldsBits[64][9];  // [n_local][e_word], padded
  int t = threadIdx.x;
  int et = blockIdx.x & 3, nt = (blockIdx.x >> 2) & 63, b = blockIdx.x >> 8;
  int e0 = et * 512, n0 = nt * 64;
  int w = t >> 6, lane = t & 63;

  const float* src = H + ((size_t)(b * N_ + n0 + w * 16)) * E_ + e0 + lane;
  for (int r4 = 0; r4 < 4; ++r4) {
    float v[4][8];
#pragma unroll
    for (int r = 0; r < 4; ++r)
#pragma unroll
      for (int wd = 0; wd < 8; ++wd)
        v[r][wd] = src[(size_t)(r4 * 4 + r) * E_ + wd * 64];
#pragma unroll
    for (int r = 0; r < 4; ++r) {
      unsigned int cnt = 0;
      int row = w * 16 + r4 * 4 + r;
#pragma unroll
      for (int wd = 0; wd < 8; ++wd) {
        unsigned long long m = __ballot(v[r][wd] != 0.0f);
        if (lane == 0) ldsBits[row][wd] = m;
        cnt += (unsigned int)__popcll(m);
      }
      if (lane == 0) atomicAdd(&deg_n[b * N_ + n0 + row], (float)cnt);
    }
  }
  __syncthreads();
  // phase 2: wave w transposes e-words 2w, 2w+1 (64 e each)
#pragma unroll
  for (int p = 0; p < 2; ++p) {
    int wd = w * 2 + p;
    unsigned long long col = ldsBits[lane][wd];  // lane = n_local
    unsigned long long mine = 0;
#pragma unroll
    for (int bit = 0; bit < 64; ++bit) {
      unsigned long long m = __ballot((col >> bit) & 1ull);  // bit i = n0+i
      if (lane == bit) mine = m;
    }
    int e = e0 + wd * 64 + lane;
    HbitsT[(((size_t)(b * E_ + e)) << 6) + nt] = mine;
    atomicAdd(&deg_e[b * E_ + e], (float)__popcll(mine));
  }
  // phase 3: copy n-major words out
  int i = t * 2;
  int row = i >> 3, wd2 = i & 7;
  unsigned long long* dst =
      Hbits + (((size_t)(b * N_ + n0 + row)) << 5) + et * 8 + wd2;
  dst[0] = ldsBits[row][wd2];
  dst[1] = ldsBits[row][wd2 + 1];
}

// ---------------------------------------------------------------------------
// K3 (phase A GEMM): p_he[ks][b][o][e] = sum_{n chunk} xtT[o][n]*H[n][e]
// grid 1024 = ks(8) x et(32) x b(4); 64o x 64e, BK=64, 8 iters.
// A staged via global_load_lds (coalesced, XOR chunk swizzle);
// B = HbitsT u64 direct loads (16 distinct 8B addrs/instr) + reg expand.
// ---------------------------------------------------------------------------
__global__ __launch_bounds__(256) void k_edge(
    const unsigned short* __restrict__ xtT,
    const unsigned long long* __restrict__ HbitsT,
    float* __restrict__ p_he) {
  __shared__ unsigned short ldsA[4096];  // [o-row][k=n] 64x64, chunk-swizzled
  int t = threadIdx.x;
  int ks = blockIdx.x & 7, et = (blockIdx.x >> 3) & 31, b = blockIdx.x >> 8;
  int e0 = et * 64;
  int w = t >> 6, lane = t & 63, quad = lane >> 4, m15 = lane & 15;

  int i0 = w * 128 + lane, i1 = i0 + 64;
  int row0 = i0 >> 3, cc0 = (i0 & 7) ^ (row0 & 7);
  int row1 = i1 >> 3, cc1 = (i1 & 7) ^ (row1 & 7);
  int gOff0 = row0 * 4096 + cc0 * 8;
  int gOff1 = row1 * 4096 + cc1 * 8;
  char* lA = (char*)ldsA;
  int lOff0 = i0 * 16, lOff1 = i1 * 16;

  const unsigned short* gA = xtT + ((size_t)b << 18) + ks * 512;
  const unsigned long long* gBt =
      HbitsT + (((size_t)(b * E_ + e0 + m15)) << 6) + ks * 8;

  int xr = m15 & 7;
  int aBase = (w * 16 + m15) * 128;
  int fs0 = (quad ^ xr) * 16, fs1 = ((4 + quad) ^ xr) * 16;

  float4v acc[4];
#pragma unroll
  for (int ct = 0; ct < 4; ++ct) acc[ct] = (float4v){0.f, 0.f, 0.f, 0.f};

  unsigned long long u0 = gBt[0], u1 = gBt[1024], u2 = gBt[2048],
                     u3 = gBt[3072];

  for (int kt = 0; kt < 8; ++kt) {
    stage16(gA + gOff0, lA + lOff0);
    stage16(gA + gOff1, lA + lOff1);
    __syncthreads();
    unsigned long long v0 = 0, v1 = 0, v2 = 0, v3 = 0;
    if (kt < 7) {  // prefetch next bit-words; overlaps MFMA below
      v0 = gBt[kt + 1];        v1 = gBt[kt + 1 + 1024];
      v2 = gBt[kt + 1 + 2048]; v3 = gBt[kt + 1 + 3072];
    }
#pragma unroll
    for (int s = 0; s < 2; ++s) {
      short8 a = *(const short8*)(lA + aBase + (s ? fs1 : fs0));
      int sh = (s * 4 + quad) << 3;
      acc[0] = __builtin_amdgcn_mfma_f32_16x16x32_bf16(
          a, expand8((unsigned int)(u0 >> sh) & 0xFFu), acc[0], 0, 0, 0);
      acc[1] = __builtin_amdgcn_mfma_f32_16x16x32_bf16(
          a, expand8((unsigned int)(u1 >> sh) & 0xFFu), acc[1], 0, 0, 0);
      acc[2] = __builtin_amdgcn_mfma_f32_16x16x32_bf16(
          a, expand8((unsigned int)(u2 >> sh) & 0xFFu), acc[2], 0, 0, 0);
      acc[3] = __builtin_amdgcn_mfma_f32_16x16x32_bf16(
          a, expand8((unsigned int)(u3 >> sh) & 0xFFu), acc[3], 0, 0, 0);
    }
    __syncthreads();
    if (kt < 7) { u0 = v0; u1 = v1; u2 = v2; u3 = v3; }
    gA += 64;
  }
  float* dst = p_he + (size_t)ks * (B_ * 64 * E_);
#pragma unroll
  for (int ct = 0; ct < 4; ++ct)
#pragma unroll
    for (int r = 0; r < 4; ++r) {
      int oo = w * 16 + quad * 4 + r;
      dst[((size_t)(b * 64 + oo)) * E_ + e0 + ct * 16 + m15] = acc[ct][r];
    }
}

// ---------------------------------------------------------------------------
// K4: heT[b][o][e] = bf16( (sum_ks p_he[ks]) / deg_e[b][e] )
// ---------------------------------------------------------------------------
__global__ __launch_bounds__(256) void k_henorm(
    const float* __restrict__ p_he, const float* __restrict__ deg_e,
    unsigned short* __restrict__ heT) {
  int idx = (blockIdx.x * 256 + threadIdx.x) * 4;  // over B*64*E = 524288
  int e = idx & (E_ - 1);
  int b = idx >> 17;
  float4 s = *(const float4*)(p_he + idx);
#pragma unroll
  for (int k = 1; k < 8; ++k) {
    float4 sk = *(const float4*)(p_he + (size_t)k * (B_ * 64 * E_) + idx);
    s.x += sk.x; s.y += sk.y; s.z += sk.z; s.w += sk.w;
  }
  float4 d = *(const float4*)(deg_e + b * E_ + e);
  unsigned int lo = (unsigned int)f2bf(s.x / d.x) |
                    ((unsigned int)f2bf(s.y / d.y) << 16);
  unsigned int hi = (unsigned int)f2bf(s.z / d.z) |
                    ((unsigned int)f2bf(s.w / d.w) << 16);
  uint2 u; u.x = lo; u.y = hi;
  *(uint2*)(heT + idx) = u;
}

// ---------------------------------------------------------------------------
// K5 (phase B GEMM): q[ks][b][n][o] = sum_{e chunk} H[n][e]*heT[o][e]
// grid 1024 = ks(4) x mt(64) x b(4); 64n x 64o, BK=64, 8 iters.
// A = Hbits u64 direct + reg expand; B staged via global_load_lds.
// ---------------------------------------------------------------------------
__global__ __launch_bounds__(256) void k_node(
    const unsigned long long* __restrict__ Hbits,
    const unsigned short* __restrict__ heT, float* __restrict__ q) {
  __shared__ unsigned short ldsB[4096];  // [o-row][k=e] swizzled
  int t = threadIdx.x;
  int ks = blockIdx.x & 3, mt = (blockIdx.x >> 2) & 63, b = blockIdx.x >> 8;
  int n0 = mt * 64;
  int w = t >> 6, lane = t & 63, quad = lane >> 4, m15 = lane & 15;

  int i0 = w * 128 + lane, i1 = i0 + 64;
  int row0 = i0 >> 3, cc0 = (i0 & 7) ^ (row0 & 7);
  int row1 = i1 >> 3, cc1 = (i1 & 7) ^ (row1 & 7);
  int gOffB0 = row0 * 2048 + cc0 * 8, gOffB1 = row1 * 2048 + cc1 * 8;
  const unsigned short* gB = heT + ((size_t)b << 17) + ks * 512;
  char* lB = (char*)ldsB;
  int lOff0 = i0 * 16, lOff1 = i1 * 16;

  const unsigned long long* gAb =
      Hbits + (((size_t)(b * N_ + n0 + w * 16 + m15)) << 5) + ks * 8;

  int xr = m15 & 7;
  int fs0 = (quad ^ xr) * 16, fs1 = ((4 + quad) ^ xr) * 16;

  float4v acc[4];
#pragma unroll
  for (int ct = 0; ct < 4; ++ct) acc[ct] = (float4v){0.f, 0.f, 0.f, 0.f};

  unsigned long long ua = gAb[0];

  for (int kt = 0; kt < 8; ++kt) {
    stage16(gB + gOffB0, lB + lOff0);
    stage16(gB + gOffB1, lB + lOff1);
    __syncthreads();
    unsigned long long va = 0;
    if (kt < 7) va = gAb[kt + 1];  // prefetch; overlaps MFMA below
#pragma unroll
    for (int s = 0; s < 2; ++s) {
      int fo = s ? fs1 : fs0;
      short8 a = expand8((unsigned int)(ua >> ((s * 4 + quad) << 3)) & 0xFFu);
#pragma unroll
      for (int ct = 0; ct < 4; ++ct) {
        short8 bb = *(const short8*)(lB + (ct * 16 + m15) * 128 + fo);
        acc[ct] = __builtin_amdgcn_mfma_f32_16x16x32_bf16(a, bb, acc[ct], 0, 0, 0);
      }
    }
    __syncthreads();
    if (kt < 7) ua = va;
    gB += 64;
  }
  float* dst = q + (size_t)ks * ((size_t)B_ * N_ * 64);
#pragma unroll
  for (int r = 0; r < 4; ++r) {
    int row = w * 16 + quad * 4 + r;
    int nn = n0 + row;
#pragma unroll
    for (int ct = 0; ct < 4; ++ct)
      dst[(((size_t)(b * N_ + nn)) << 6) + ct * 16 + m15] = acc[ct][r];
  }
}

// ---------------------------------------------------------------------------
// K6: out[b][n][o] = (sum_ks q[ks]) / deg_n[b][n] + bias[o]
// ---------------------------------------------------------------------------
__global__ __launch_bounds__(256) void k_final(
    const float* __restrict__ q, const float* __restrict__ deg_n,
    const float* __restrict__ bias, float* __restrict__ out) {
  int idx = (blockIdx.x * 256 + threadIdx.x) * 4;  // over B*N*64 = 1048576
  int o = idx & 63;
  int bn = idx >> 6;
  float4 s = *(const float4*)(q + idx);
#pragma unroll
  for (int k = 1; k < 4; ++k) {
    float4 sk = *(const float4*)(q + (size_t)k * ((size_t)B_ * N_ * 64) + idx);
    s.x += sk.x; s.y += sk.y; s.z += sk.z; s.w += sk.w;
  }
  float4 bv = *(const float4*)(bias + o);
  float inv = 1.0f / deg_n[bn];
  float4 r;
  r.x = s.x * inv + bv.x; r.y = s.y * inv + bv.y;
  r.z = s.z * inv + bv.z; r.w = s.w * inv + bv.w;
  *(float4*)(out + idx) = r;
}

extern "C" void kernel_launch(void* const* d_in, const int* in_sizes, int n_in,
                              void* d_out, int out_size, void* d_ws, size_t ws_size,
                              hipStream_t stream) {
  const float* x     = (const float*)d_in[0];
  const float* H     = (const float*)d_in[1];
  const float* theta = (const float*)d_in[2];
  const float* bias  = (const float*)d_in[3];

  // ws (bytes): xtT 2MB | Hbits 4MB | HbitsT 4MB | p_he 16MB | heT 1MB |
  //             q 16MB | deg_e 32KB | deg_n 64KB   (~43 MB)
  char* ws = (char*)d_ws;
  unsigned short* xtT         = (unsigned short*)ws;
  unsigned long long* Hbits   = (unsigned long long*)(ws + 2097152);
  unsigned long long* HbitsT  = (unsigned long long*)(ws + 6291456);
  float* p_he                 = (float*)(ws + 10485760);
  unsigned short* heT         = (unsigned short*)(ws + 27262976);
  float* q                    = (float*)(ws + 28311552);
  float* deg_e                = (float*)(ws + 45088768);
  float* deg_n                = (float*)(ws + 45121536);

  hipMemsetAsync(deg_e, 0, 98304, stream);  // deg_e + deg_n (adjacent)
  k_transform<<<256, 256, 0, stream>>>(x, theta, xtT);
  k_prep<<<1024, 256, 0, stream>>>(H, Hbits, HbitsT, deg_e, deg_n);
  k_edge<<<1024, 256, 0, stream>>>(xtT, HbitsT, p_he);
  k_henorm<<<512, 256, 0, stream>>>(p_he, deg_e, heT);
  k_node<<<1024, 256, 0, stream>>>(Hbits, heT, q);
  k_final<<<1024, 256, 0, stream>>>(q, deg_n, bias, (float*)d_out);
}